// Round 2
// baseline (405.834 us; speedup 1.0000x reference)
//
#include <hip/hip_runtime.h>
#include <math.h>

// MAPLoss: loss = mean_{b,m,n}[ 0.5*T^t Sy^{-1} T + 0.5*log(clip(det Sy, EPS)) ]
//          zeroed if max(t1) > 1e7.
// B=16, C=3, M=512, N=512. target/mu: [B,C,M,N]; sigma_y: [B,M,N,3,3].
// sigma_mu (d_in[2]) / sigma_n (d_in[3]) unused by the math.
//
// R5: counters showed a concurrency limit, not a mechanism limit:
//     block lifetime ~33k cy vs ~2k cy critical path, 9.6 waves/CU resident
//     (36.5 KB LDS capped 4 blocks/CU; measured 2.4). Fix = pure TLP:
//     1 pixel/thread, PPB=256, LDS 12 KB/block -> 8 blocks = 32 waves/CU
//     (occupancy cap 100%), 16384 blocks. Same math/reduction structure.
//     Sigma staged via global_load_lds w=16 (3 rounds of 256 f4, padded to
//     768 with clamped global addrs; LDS dest stays linear = gl_lds contract).
//     LDS readback stride 36 B: 9 coprime 32 -> <=2 lanes/bank (free, m136).

#define EPS_F 1e-06f
#define T1_CLIP_F 1e7f

constexpr long long MN = 512LL * 512LL;           // 262144 = 2^18
constexpr long long P  = 16LL * MN;               // 4194304 pixels
constexpr int TPB  = 256;
constexpr int PPB  = 256;                         // 1 pixel per thread
constexpr int NBLK = (int)(P / PPB);              // 16384
constexpr int SF4  = PPB * 9 / 4;                 // 576 f4 of sigma per block
constexpr int SF4_PAD = 3 * TPB;                  // 768 staged (tail garbage unread)
constexpr long long SIGF4 = P * 9 / 4;            // 9437184 f4 total

__device__ __forceinline__ void pixel_eval(
    float t0, float t1, float t2,
    float s00, float s01, float s02,
    float s10, float s11, float s12,
    float s20, float s21, float s22,
    float& t1v, float& dets)
{
    const float c00 = s11*s22 - s12*s21;
    const float c01 = s12*s20 - s10*s22;
    const float c02 = s10*s21 - s11*s20;
    const float det = s00*c00 + s01*c01 + s02*c02;

    const float a01 = s02*s21 - s01*s22;
    const float a02 = s01*s12 - s02*s11;
    const float a11 = s00*s22 - s02*s20;
    const float a12 = s02*s10 - s00*s12;
    const float a21 = s01*s20 - s00*s21;
    const float a22 = s00*s11 - s01*s10;

    const float q = t0*(c00*t0 + a01*t1 + a02*t2)
                  + t1*(c01*t0 + a11*t1 + a12*t2)
                  + t2*(c02*t0 + a21*t1 + a22*t2);

    t1v  = 0.5f * q / det;
    dets = 0.5f * logf(fmaxf(det, EPS_F));
}

__global__ __launch_bounds__(TPB, 8) void map_partial(
    const float* __restrict__ target, const float* __restrict__ mu,
    const float* __restrict__ sigma, double* __restrict__ psum,
    float* __restrict__ pmax)
{
    __shared__ float4 sh[SF4_PAD];                // 12 KB
    const int t = threadIdx.x;

    const long long blk_p0 = (long long)blockIdx.x * PPB;   // first pixel of block
    const long long sf0    = (long long)blockIdx.x * SF4;   // first sigma f4

    // ---- stage sigma: async global->LDS, width 16, no VGPR roundtrip ----
    // LDS dest linear in lane order (wave-uniform base + lane*16). Global
    // addr clamped for the padded tail (those LDS slots are never read).
    #pragma unroll
    for (int k = 0; k < 3; ++k) {
        long long gi = sf0 + k * TPB + t;
        if (gi >= SIGF4) gi = SIGF4 - 1;
        __builtin_amdgcn_global_load_lds(
            (const __attribute__((address_space(1))) void*)((const float4*)sigma + gi),
            (__attribute__((address_space(3))) void*)(&sh[k * TPB + t]),
            16, 0, 0);
    }

    // ---- target/mu: coalesced scalar loads (1 pixel/thread), issued in the
    //      same window so they overlap the LDS staging ----
    const long long p0 = blk_p0 + t;              // this thread's pixel
    const long long b  = p0 >> 18;                // p0 / MN
    const long long r  = p0 & (MN - 1);
    const long long tb = b * (3 * MN) + r;

    const float tg0 = target[tb];
    const float tg1 = target[tb + MN];
    const float tg2 = target[tb + 2*MN];
    const float m0  = mu[tb];
    const float m1  = mu[tb + MN];
    const float m2  = mu[tb + 2*MN];

    __syncthreads();   // drains vmcnt(0): staging complete

    // ---- read back this thread's pixel (9 floats at byte stride 36) ----
    const float* s = (const float*)sh + 9 * t;
    const float s00 = s[0], s01 = s[1], s02 = s[2];
    const float s10 = s[3], s11 = s[4], s12 = s[5];
    const float s20 = s[6], s21 = s[7], s22 = s[8];

    float t1v, dets;
    pixel_eval(tg0 - m0, tg1 - m1, tg2 - m2,
               s00, s01, s02, s10, s11, s12, s20, s21, s22,
               t1v, dets);
    double acc = (double)(t1v + dets);
    float  mx  = t1v;                // t1 >= 0 (Sy is SPD)

    // ---- wave-64 shuffle reduce ----
    for (int off = 32; off > 0; off >>= 1) {
        acc += __shfl_down(acc, off, 64);
        mx = fmaxf(mx, __shfl_down(mx, off, 64));
    }
    __shared__ double ssum[TPB / 64];
    __shared__ float  smax[TPB / 64];
    const int lane = t & 63;
    const int wv   = t >> 6;
    if (lane == 0) { ssum[wv] = acc; smax[wv] = mx; }
    __syncthreads();
    if (t == 0) {
        double a = ssum[0] + ssum[1] + ssum[2] + ssum[3];
        float  m = fmaxf(fmaxf(smax[0], smax[1]), fmaxf(smax[2], smax[3]));
        psum[blockIdx.x] = a;
        pmax[blockIdx.x] = m;
    }
}

__global__ __launch_bounds__(TPB) void map_final(
    const double* __restrict__ psum, const float* __restrict__ pmax,
    float* __restrict__ out)
{
    double acc = 0.0;
    float mx = 0.0f;
    for (int i = threadIdx.x; i < NBLK; i += TPB) {
        acc += psum[i];
        mx = fmaxf(mx, pmax[i]);
    }
    for (int off = 32; off > 0; off >>= 1) {
        acc += __shfl_down(acc, off, 64);
        mx = fmaxf(mx, __shfl_down(mx, off, 64));
    }
    __shared__ double ssum[TPB / 64];
    __shared__ float  smax[TPB / 64];
    const int lane = threadIdx.x & 63;
    const int wv   = threadIdx.x >> 6;
    if (lane == 0) { ssum[wv] = acc; smax[wv] = mx; }
    __syncthreads();
    if (threadIdx.x == 0) {
        double a = ssum[0] + ssum[1] + ssum[2] + ssum[3];
        float  m = fmaxf(fmaxf(smax[0], smax[1]), fmaxf(smax[2], smax[3]));
        float loss = (float)(a / (double)P);
        out[0] = (m > T1_CLIP_F) ? 0.0f : loss;
    }
}

extern "C" void kernel_launch(void* const* d_in, const int* in_sizes, int n_in,
                              void* d_out, int out_size, void* d_ws, size_t ws_size,
                              hipStream_t stream) {
    const float* target  = (const float*)d_in[0];
    const float* mu      = (const float*)d_in[1];
    // d_in[2] = sigma_mu, d_in[3] = sigma_n : unused
    const float* sigma_y = (const float*)d_in[4];

    double* psum = (double*)d_ws;                                 // NBLK doubles
    float*  pmax = (float*)((char*)d_ws + NBLK * sizeof(double)); // NBLK floats

    map_partial<<<NBLK, TPB, 0, stream>>>(target, mu, sigma_y, psum, pmax);
    map_final<<<1, TPB, 0, stream>>>(psum, pmax, (float*)d_out);
}

// Round 3
// 395.303 us; speedup vs baseline: 1.0266x; 1.0266x over previous
//
#include <hip/hip_runtime.h>
#include <math.h>

// MAPLoss: loss = mean_{b,m,n}[ 0.5*T^t Sy^{-1} T + 0.5*log(clip(det Sy, EPS)) ]
//          zeroed if max(t1) > 1e7.
// B=16, C=3, M=512, N=512. target/mu: [B,C,M,N]; sigma_y: [B,M,N,3,3].
// sigma_mu (d_in[2]) / sigma_n (d_in[3]) unused by the math.
//
// R6: R3/R4/R5 all pinned at 2.7 TB/s combined read regardless of staging
//     mechanism or occupancy -> the shared drain rhythm (vmcnt(0)+barrier
//     every ~15KB, block churn) is the suspect. This version: persistent
//     independent waves, zero barriers in the main loop, double-buffered
//     per-wave LDS sigma tile, counted s_waitcnt vmcnt(15) so each wave
//     always keeps one full chunk (15 vmem ops) in flight (T3/T4 pattern).
//     512 blocks x 4 waves, 8 chunks of 256 px per wave.
//     lgkmcnt(0) before each re-stage closes the ds_read/gl_lds WAR race.

#define EPS_F 1e-06f
#define T1_CLIP_F 1e7f

constexpr long long MN = 512LL * 512LL;           // 262144 = 2^18
constexpr long long P  = 16LL * MN;               // 4194304 pixels
constexpr int TPB   = 256;
constexpr int WAVES = TPB / 64;                   // 4 independent waves/block
constexpr int CHPX  = 256;                        // pixels per chunk (per wave)
constexpr int CHF4  = CHPX * 9 / 4;               // 576 f4 sigma per chunk
constexpr int CPW   = 8;                          // chunks per wave
constexpr long long NCHUNK = P / CHPX;            // 16384
constexpr int NBLK  = (int)(NCHUNK / (CPW * WAVES));  // 512

__device__ __forceinline__ void pixel_eval(
    float t0, float t1, float t2,
    float s00, float s01, float s02,
    float s10, float s11, float s12,
    float s20, float s21, float s22,
    float& t1v, float& dets)
{
    const float c00 = s11*s22 - s12*s21;
    const float c01 = s12*s20 - s10*s22;
    const float c02 = s10*s21 - s11*s20;
    const float det = s00*c00 + s01*c01 + s02*c02;

    const float a01 = s02*s21 - s01*s22;
    const float a02 = s01*s12 - s02*s11;
    const float a11 = s00*s22 - s02*s20;
    const float a12 = s02*s10 - s00*s12;
    const float a21 = s01*s20 - s00*s21;
    const float a22 = s00*s11 - s01*s10;

    const float q = t0*(c00*t0 + a01*t1 + a02*t2)
                  + t1*(c01*t0 + a11*t1 + a12*t2)
                  + t2*(c02*t0 + a21*t1 + a22*t2);

    t1v  = 0.5f * q / det;
    dets = 0.5f * logf(fmaxf(det, EPS_F));
}

__global__ __launch_bounds__(TPB, 2) void map_partial(
    const float* __restrict__ target, const float* __restrict__ mu,
    const float* __restrict__ sigma, double* __restrict__ psum,
    float* __restrict__ pmax)
{
    __shared__ float4 sh[WAVES][2][CHF4];         // 72 KB: per-wave double buffer
    const int t    = threadIdx.x;
    const int lane = t & 63;
    const int wv   = t >> 6;

    const long long gw  = (long long)blockIdx.x * WAVES + wv;   // global wave id
    const long long ck0 = gw * CPW;                              // first chunk

    double acc = 0.0;
    float  mx  = 0.0f;                            // t1 >= 0 (Sy is SPD)
    float4 TG[2][3], MM[2][3];                    // cur/next target-mu (static idx after unroll)

    // stage one chunk's sigma (9 rounds x 64 lanes x 16B) into wave-private LDS
    auto stage = [&](int par, long long ck) {
        const float4* sp = (const float4*)sigma + ck * CHF4;
        #pragma unroll
        for (int k = 0; k < 9; ++k) {
            __builtin_amdgcn_global_load_lds(
                (const __attribute__((address_space(1))) void*)(sp + k * 64 + lane),
                (__attribute__((address_space(3))) void*)(&sh[wv][par][k * 64 + lane]),
                16, 0, 0);
        }
    };
    // 6 coalesced float4 loads (4 consecutive pixels of target/mu)
    auto loadTM = [&](long long ck, float4* T4, float4* M4) {
        const long long p0 = ck * CHPX + 4LL * lane;
        const long long b  = p0 >> 18;            // p0 / MN (chunk never spans b)
        const long long r  = p0 & (MN - 1);
        const long long tb = b * (3 * MN) + r;
        T4[0] = *(const float4*)(target + tb);
        T4[1] = *(const float4*)(target + tb + MN);
        T4[2] = *(const float4*)(target + tb + 2 * MN);
        M4[0] = *(const float4*)(mu + tb);
        M4[1] = *(const float4*)(mu + tb + MN);
        M4[2] = *(const float4*)(mu + tb + 2 * MN);
    };
    // 4 pixels: 9x ds_read_b128 at 144B lane stride (measured conflict-free, R3)
    auto compute = [&](int par, const float4* T4, const float4* M4) {
        const float4* f = &sh[wv][par][0] + 9 * lane;
        const float4 f0 = f[0], f1 = f[1], f2 = f[2];
        const float4 f3 = f[3], f4_ = f[4], f5 = f[5];
        const float4 f6 = f[6], f7 = f[7], f8 = f[8];
        float t1v, dets;
        pixel_eval(T4[0].x - M4[0].x, T4[1].x - M4[1].x, T4[2].x - M4[2].x,
                   f0.x, f0.y, f0.z, f0.w, f1.x, f1.y, f1.z, f1.w, f2.x,
                   t1v, dets);
        acc += (double)(t1v + dets); mx = fmaxf(mx, t1v);
        pixel_eval(T4[0].y - M4[0].y, T4[1].y - M4[1].y, T4[2].y - M4[2].y,
                   f2.y, f2.z, f2.w, f3.x, f3.y, f3.z, f3.w, f4_.x, f4_.y,
                   t1v, dets);
        acc += (double)(t1v + dets); mx = fmaxf(mx, t1v);
        pixel_eval(T4[0].z - M4[0].z, T4[1].z - M4[1].z, T4[2].z - M4[2].z,
                   f4_.z, f4_.w, f5.x, f5.y, f5.z, f5.w, f6.x, f6.y, f6.z,
                   t1v, dets);
        acc += (double)(t1v + dets); mx = fmaxf(mx, t1v);
        pixel_eval(T4[0].w - M4[0].w, T4[1].w - M4[1].w, T4[2].w - M4[2].w,
                   f6.w, f7.x, f7.y, f7.z, f7.w, f8.x, f8.y, f8.z, f8.w,
                   t1v, dets);
        acc += (double)(t1v + dets); mx = fmaxf(mx, t1v);
    };

    // ---- prologue: chunk 0 in flight ----
    stage(0, ck0);
    loadTM(ck0, TG[0], MM[0]);

    // ---- steady loop: never drain vmcnt to 0, no barriers ----
    #pragma unroll
    for (int cc = 0; cc < CPW; ++cc) {
        if (cc + 1 < CPW) {
            // buffer (cc+1)&1 was ds_read at iter cc-1: ensure those reads
            // completed before gl_lds rewrites it (WAR on LDS).
            asm volatile("s_waitcnt lgkmcnt(0)" ::: "memory");
            stage((cc + 1) & 1, ck0 + cc + 1);
            loadTM(ck0 + cc + 1, TG[(cc + 1) & 1], MM[(cc + 1) & 1]);
            // chunk cc's 15 vmem ops are the oldest; chunk cc+1's 15 stay in flight
            asm volatile("s_waitcnt vmcnt(15)" ::: "memory");
        } else {
            asm volatile("s_waitcnt vmcnt(0)" ::: "memory");
        }
        compute(cc & 1, TG[cc & 1], MM[cc & 1]);
    }

    // ---- wave-64 shuffle reduce, then cross-wave via LDS ----
    for (int off = 32; off > 0; off >>= 1) {
        acc += __shfl_down(acc, off, 64);
        mx = fmaxf(mx, __shfl_down(mx, off, 64));
    }
    __shared__ double ssum[WAVES];
    __shared__ float  smax[WAVES];
    if (lane == 0) { ssum[wv] = acc; smax[wv] = mx; }
    __syncthreads();
    if (t == 0) {
        double a = ssum[0] + ssum[1] + ssum[2] + ssum[3];
        float  m = fmaxf(fmaxf(smax[0], smax[1]), fmaxf(smax[2], smax[3]));
        psum[blockIdx.x] = a;
        pmax[blockIdx.x] = m;
    }
}

__global__ __launch_bounds__(TPB) void map_final(
    const double* __restrict__ psum, const float* __restrict__ pmax,
    float* __restrict__ out)
{
    double acc = 0.0;
    float mx = 0.0f;
    for (int i = threadIdx.x; i < NBLK; i += TPB) {
        acc += psum[i];
        mx = fmaxf(mx, pmax[i]);
    }
    for (int off = 32; off > 0; off >>= 1) {
        acc += __shfl_down(acc, off, 64);
        mx = fmaxf(mx, __shfl_down(mx, off, 64));
    }
    __shared__ double ssum[TPB / 64];
    __shared__ float  smax[TPB / 64];
    const int lane = threadIdx.x & 63;
    const int wv   = threadIdx.x >> 6;
    if (lane == 0) { ssum[wv] = acc; smax[wv] = mx; }
    __syncthreads();
    if (threadIdx.x == 0) {
        double a = ssum[0] + ssum[1] + ssum[2] + ssum[3];
        float  m = fmaxf(fmaxf(smax[0], smax[1]), fmaxf(smax[2], smax[3]));
        float loss = (float)(a / (double)P);
        out[0] = (m > T1_CLIP_F) ? 0.0f : loss;
    }
}

extern "C" void kernel_launch(void* const* d_in, const int* in_sizes, int n_in,
                              void* d_out, int out_size, void* d_ws, size_t ws_size,
                              hipStream_t stream) {
    const float* target  = (const float*)d_in[0];
    const float* mu      = (const float*)d_in[1];
    // d_in[2] = sigma_mu, d_in[3] = sigma_n : unused
    const float* sigma_y = (const float*)d_in[4];

    double* psum = (double*)d_ws;                                 // NBLK doubles
    float*  pmax = (float*)((char*)d_ws + NBLK * sizeof(double)); // NBLK floats

    map_partial<<<NBLK, TPB, 0, stream>>>(target, mu, sigma_y, psum, pmax);
    map_final<<<1, TPB, 0, stream>>>(psum, pmax, (float*)d_out);
}